// Round 10
// baseline (291.372 us; speedup 1.0000x reference)
//
#include <hip/hip_runtime.h>

#define DEVFN __device__ __forceinline__

typedef unsigned short u16;
typedef __attribute__((ext_vector_type(8))) unsigned short u16x8;
typedef __attribute__((ext_vector_type(4))) unsigned short u16x4;
typedef __attribute__((ext_vector_type(8))) __bf16 bf16x8;
typedef __attribute__((ext_vector_type(4))) float f32x4;

// ---------- helpers ----------
DEVFN u16 f2bf_hw(float f) {  // hardware RNE convert (single v_cvt)
    return __builtin_bit_cast(u16, (__bf16)f);
}

DEVFN float bf2f(u16 h) {
    unsigned u = (unsigned)h << 16;
    return __builtin_bit_cast(float, u);
}

DEVFN bf16x8 ldfrag(const u16* p) {
    return __builtin_bit_cast(bf16x8, *(const u16x8*)p);
}

DEVFN f32x4 mfma16(bf16x8 a, bf16x8 b, f32x4 c) {
    return __builtin_amdgcn_mfma_f32_16x16x32_bf16(a, b, c, 0, 0, 0);
}

// async global->LDS, 16B per lane; l must be the wave-uniform base
DEVFN void async16(const u16* g, u16* l) {
    __builtin_amdgcn_global_load_lds(
        (const __attribute__((address_space(1))) void*)g,
        (__attribute__((address_space(3))) void*)l, 16, 0, 0);
}

// ---------- fp32->bf16 converts + mask compaction, ONE dispatch ----------
// blocks 0..8191: y. 8192..12287: weights. block 12288: mask compaction.
__global__ __launch_bounds__(256) void conv_all(const float* __restrict__ y,
                                                const float* __restrict__ w0,
                                                const float* __restrict__ w1,
                                                const float* __restrict__ w2,
                                                const float* __restrict__ w3,
                                                u16* __restrict__ yb,
                                                u16* __restrict__ wb,
                                                const int* __restrict__ mask,
                                                int* __restrict__ idx,
                                                int* __restrict__ cnt) {
    const int b = blockIdx.x;
    if (b >= 12288) {
        const int wave = threadIdx.x >> 6, lane = threadIdx.x & 63;
        for (int bb = wave; bb < 8; bb += 4) {
            const int* m = mask + bb * 1024;
            int* ib = idx + bb * 1024;
            int base = 0;
            for (int t = 0; t < 16; ++t) {
                const int pos = t * 64 + lane;
                const int valid = (m[pos] == 0) ? 1 : 0;
                const unsigned long long bal = __ballot(valid);
                const int pre = __popcll(bal & ((1ull << lane) - 1ull));
                if (valid) ib[base + pre] = pos;
                base += (int)__popcll(bal);
            }
            if (lane == 0) cnt[bb] = base;
            for (int i = base + lane; i < 1024; i += 64) ib[i] = 0;  // safe pad
        }
        return;
    }
    const float* src;
    u16* dst;
    int i;
    if (b < 8192) {
        src = y; dst = yb;
        i = b * 1024 + threadIdx.x * 4;
    } else {
        const int g = (b - 8192) >> 10;
        src = g == 0 ? w0 : (g == 1 ? w1 : (g == 2 ? w2 : w3));
        dst = wb + (size_t)g * 1024 * 1024;
        i = ((b - 8192) & 1023) * 1024 + threadIdx.x * 4;
    }
    const float4 v = *(const float4*)&src[i];
    u16x4 o;
    o.x = f2bf_hw(v.x); o.y = f2bf_hw(v.y);
    o.z = f2bf_hw(v.z); o.w = f2bf_hw(v.w);
    *(u16x4*)&dst[i] = o;
}

// ---------- GEMM: C[M,N] = A[M,K] * Bt[N,K]^T + bias, bf16 out ----------
// EXACT round-7 kernel (73.4 us QKV, MfmaUtil 28.7%). Round-8 lesson: adding
// split-K/runtime-ld machinery to this signature degraded the K-loop schedule
// (same MFMA count, MfmaUtil 28.7->24.5) — keep this hot path untouched.
// BK=32, n-fast 2D grid, launch_bounds(256,4) -> 56 VGPR, 32% occupancy.
// Output split by col>>10 into up to 3 dense [M,1024] buffers (QKV fusion).
__global__ __launch_bounds__(256, 4) void gemm_bt(const u16* __restrict__ A,
                                                  const u16* __restrict__ Bt,
                                                  const float* __restrict__ b0,
                                                  const float* __restrict__ b1,
                                                  const float* __restrict__ b2,
                                                  u16* __restrict__ C0,
                                                  u16* __restrict__ C1,
                                                  u16* __restrict__ C2,
                                                  int K) {
    __shared__ u16 lA[128 * 32];
    __shared__ u16 lB[128 * 32];
    const int tid = threadIdx.x;
    const int wave = tid >> 6, lane = tid & 63;
    const int quad = lane >> 4, l16 = lane & 15;
    const int n0 = blockIdx.x * 128, m0 = blockIdx.y * 128;
    const int wm = (wave >> 1) * 64, wn = (wave & 1) * 64;
    const int srow = tid >> 2, scol = (tid & 3) * 8;
    const u16* Ag0 = A + (size_t)(m0 + srow) * K + scol;
    const u16* Ag1 = A + (size_t)(m0 + 64 + srow) * K + scol;
    const u16* Bg0 = Bt + (size_t)(n0 + srow) * K + scol;
    const u16* Bg1 = Bt + (size_t)(n0 + 64 + srow) * K + scol;
    u16* lA0 = &lA[wave * 512];
    u16* lA1 = &lA[2048 + wave * 512];
    u16* lB0 = &lB[wave * 512];
    u16* lB1 = &lB[2048 + wave * 512];
    f32x4 acc[4][4] = {};
    for (int k0 = 0; k0 < K; k0 += 32) {
        __syncthreads();
        async16(Ag0 + k0, lA0);
        async16(Ag1 + k0, lA1);
        async16(Bg0 + k0, lB0);
        async16(Bg1 + k0, lB1);
        __syncthreads();
        bf16x8 af[4], bfr[4];
        #pragma unroll
        for (int i = 0; i < 4; ++i)
            af[i] = ldfrag(&lA[(wm + i * 16 + l16) * 32 + quad * 8]);
        #pragma unroll
        for (int i = 0; i < 4; ++i)
            bfr[i] = ldfrag(&lB[(wn + i * 16 + l16) * 32 + quad * 8]);
        #pragma unroll
        for (int mi = 0; mi < 4; ++mi)
            #pragma unroll
            for (int ni = 0; ni < 4; ++ni)
                acc[mi][ni] = mfma16(af[mi], bfr[ni], acc[mi][ni]);
    }
    #pragma unroll
    for (int mi = 0; mi < 4; ++mi) {
        #pragma unroll
        for (int ni = 0; ni < 4; ++ni) {
            const int col = n0 + wn + ni * 16 + l16;
            const int cs = col >> 10;          // uniform per 16-col group
            const int c = col & 1023;
            const float* bp = cs == 0 ? b0 : (cs == 1 ? b1 : b2);
            u16* cp = cs == 0 ? C0 : (cs == 1 ? C1 : C2);
            const float bb = bp[c];
            #pragma unroll
            for (int r = 0; r < 4; ++r) {
                const int row = m0 + wm + mi * 16 + quad * 4 + r;
                cp[(size_t)row * 1024 + c] = f2bf_hw(acc[mi][ni][r] + bb);
            }
        }
    }
}

// ---------- split-K GEMM clone for M-proj (separate kernel on purpose) ----------
// All strides compile-time (K=512 per half, ld=1024). bx<8: K[0,512)+bias->X0;
// bx>=8: K[512,1024), no bias ->X1. ln_res sums the bf16 partials.
// 1024 blocks = 4/CU (vs 512 = 2/CU unsplit). Round-8 lesson: this lives in
// its own kernel so the QKV gemm_bt codegen is untouched.
__global__ __launch_bounds__(256, 4) void gemm_sk(const u16* __restrict__ A,
                                                  const u16* __restrict__ Bt,
                                                  const float* __restrict__ bias,
                                                  u16* __restrict__ X0,
                                                  u16* __restrict__ X1) {
    __shared__ u16 lA[128 * 32];
    __shared__ u16 lB[128 * 32];
    const int tid = threadIdx.x;
    const int wave = tid >> 6, lane = tid & 63;
    const int quad = lane >> 4, l16 = lane & 15;
    const int bx = blockIdx.x;
    const int half = bx >> 3;                 // 0 or 1
    const int n0 = (bx & 7) * 128, m0 = blockIdx.y * 128;
    const int wm = (wave >> 1) * 64, wn = (wave & 1) * 64;
    const int srow = tid >> 2, scol = (tid & 3) * 8;
    const int koff = half * 512;
    const u16* Ag0 = A + (size_t)(m0 + srow) * 1024 + koff + scol;
    const u16* Ag1 = A + (size_t)(m0 + 64 + srow) * 1024 + koff + scol;
    const u16* Bg0 = Bt + (size_t)(n0 + srow) * 1024 + koff + scol;
    const u16* Bg1 = Bt + (size_t)(n0 + 64 + srow) * 1024 + koff + scol;
    u16* lA0 = &lA[wave * 512];
    u16* lA1 = &lA[2048 + wave * 512];
    u16* lB0 = &lB[wave * 512];
    u16* lB1 = &lB[2048 + wave * 512];
    f32x4 acc[4][4] = {};
    for (int k0 = 0; k0 < 512; k0 += 32) {
        __syncthreads();
        async16(Ag0 + k0, lA0);
        async16(Ag1 + k0, lA1);
        async16(Bg0 + k0, lB0);
        async16(Bg1 + k0, lB1);
        __syncthreads();
        bf16x8 af[4], bfr[4];
        #pragma unroll
        for (int i = 0; i < 4; ++i)
            af[i] = ldfrag(&lA[(wm + i * 16 + l16) * 32 + quad * 8]);
        #pragma unroll
        for (int i = 0; i < 4; ++i)
            bfr[i] = ldfrag(&lB[(wn + i * 16 + l16) * 32 + quad * 8]);
        #pragma unroll
        for (int mi = 0; mi < 4; ++mi)
            #pragma unroll
            for (int ni = 0; ni < 4; ++ni)
                acc[mi][ni] = mfma16(af[mi], bfr[ni], acc[mi][ni]);
    }
    u16* cp = half ? X1 : X0;
    #pragma unroll
    for (int mi = 0; mi < 4; ++mi) {
        #pragma unroll
        for (int ni = 0; ni < 4; ++ni) {
            const int col = n0 + wn + ni * 16 + l16;
            const float bb = half ? 0.0f : bias[col];
            #pragma unroll
            for (int r = 0; r < 4; ++r) {
                const int row = m0 + wm + mi * 16 + quad * 4 + r;
                cp[(size_t)row * 1024 + col] = f2bf_hw(acc[mi][ni][r] + bb);
            }
        }
    }
}

// ---------- flash attention over COMPACTED K/V, in-kernel V transpose ----------
// Only unmasked K-positions processed (math identical: masked cols had
// exp(-1e9)=0 exactly). 128 q-rows/block, each wave owns 2x16 rows.
__global__ __launch_bounds__(256) void attn(const u16* __restrict__ qb,
                                            const u16* __restrict__ kb,
                                            const u16* __restrict__ vb,
                                            const int* __restrict__ idxb,
                                            const int* __restrict__ cntb,
                                            u16* __restrict__ attb) {
    // XCD swizzle: 8 q-tiles of one (b,h) land on one XCD; 16 heads/XCD
    // keeps that XCD's K+V (4 MB) resident in its L2.
    const int lin = blockIdx.x;
    const int xcd = lin & 7, slot = lin >> 3;          // slot 0..127
    const int bh = xcd * 16 + (slot >> 3);
    const int q0 = (slot & 7) * 128;
    const int bb = bh >> 4, h = bh & 15;
    const int tid = threadIdx.x, wave = tid >> 6, lane = tid & 63;
    const int quad = lane >> 4, l16 = lane & 15;
    __shared__ u16 lK[64 * 72];
    __shared__ u16 lV[64 * 72];
    __shared__ u16 lP[128 * 72];

    const int cn = cntb[bb];
    const int kEnd = (cn + 63) & ~63;
    const int* ib = idxb + bb * 1024;

    // Q fragments: 2 row-groups x 2 k-halves
    bf16x8 aq[2][2];
    #pragma unroll
    for (int rg = 0; rg < 2; ++rg) {
        const int qrow = q0 + wave * 32 + rg * 16 + l16;
        const u16* qp = qb + (size_t)(bb * 1024 + qrow) * 1024 + h * 64 + quad * 8;
        aq[rg][0] = ldfrag(qp);
        aq[rg][1] = ldfrag(qp + 32);
    }

    f32x4 o[2][4] = {};
    float ps_acc[2][4] = {};

    const int srow = tid >> 3, scol = (tid & 7) * 8;
    const u16* kbase = kb + (size_t)(bb * 1024) * 1024 + h * 64 + scol;
    const u16* vbase = vb + (size_t)(bb * 1024) * 1024 + h * 64 + scol;

    // prefetch tile 0: K and V rows gathered via idx (same gi for both)
    int gi0 = ib[srow], gi1 = ib[srow + 32];
    u16x8 nk0 = *(const u16x8*)(kbase + (size_t)gi0 * 1024);
    u16x8 nk1 = *(const u16x8*)(kbase + (size_t)gi1 * 1024);
    u16x8 nv0 = *(const u16x8*)(vbase + (size_t)gi0 * 1024);
    u16x8 nv1 = *(const u16x8*)(vbase + (size_t)gi1 * 1024);

    const float C = 0.18033688011112043f;  // 0.125 * log2(e)

    for (int kt = 0; kt < kEnd; kt += 64) {
        __syncthreads();
        *(u16x8*)&lK[srow * 72 + scol] = nk0;
        *(u16x8*)&lK[(srow + 32) * 72 + scol] = nk1;
        // V written transposed: lV[d][slot]; ~2-way bank aliasing (free).
        #pragma unroll
        for (int j = 0; j < 8; ++j) {
            lV[(scol + j) * 72 + srow] = nv0[j];
            lV[(scol + j) * 72 + srow + 32] = nv1[j];
        }
        __syncthreads();
        const int ktn = kt + 64;
        if (ktn < kEnd) {  // prefetch next tile; vmcnt hidden behind compute
            gi0 = ib[ktn + srow]; gi1 = ib[ktn + srow + 32];
            nk0 = *(const u16x8*)(kbase + (size_t)gi0 * 1024);
            nk1 = *(const u16x8*)(kbase + (size_t)gi1 * 1024);
            nv0 = *(const u16x8*)(vbase + (size_t)gi0 * 1024);
            nv1 = *(const u16x8*)(vbase + (size_t)gi1 * 1024);
        }

        // K fragments loaded once, reused by both row-groups
        bf16x8 kf[4][2];
        #pragma unroll
        for (int n = 0; n < 4; ++n) {
            kf[n][0] = ldfrag(&lK[(n * 16 + l16) * 72 + quad * 8]);
            kf[n][1] = ldfrag(&lK[(n * 16 + l16) * 72 + 32 + quad * 8]);
        }
        f32x4 s[2][4];
        #pragma unroll
        for (int rg = 0; rg < 2; ++rg)
            #pragma unroll
            for (int n = 0; n < 4; ++n) {
                f32x4 t = {};
                t = mfma16(aq[rg][0], kf[n][0], t);
                t = mfma16(aq[rg][1], kf[n][1], t);
                s[rg][n] = t;
            }
        float bias[4];
        #pragma unroll
        for (int n = 0; n < 4; ++n)
            bias[n] = (kt + n * 16 + l16 < cn) ? 0.0f : -1e9f;
        #pragma unroll
        for (int rg = 0; rg < 2; ++rg)
            #pragma unroll
            for (int n = 0; n < 4; ++n)
                #pragma unroll
                for (int r = 0; r < 4; ++r) {
                    const float p =
                        __builtin_amdgcn_exp2f(__builtin_fmaf(s[rg][n][r], C, bias[n]));
                    ps_acc[rg][r] += p;
                    lP[(wave * 32 + rg * 16 + quad * 4 + r) * 72 + n * 16 + l16] =
                        f2bf_hw(p);
                }
        // lP rows are wave-private: drain this wave's LDS ops, no barrier
        __asm__ __volatile__("s_waitcnt lgkmcnt(0)" ::: "memory");
        bf16x8 ap[2][2];
        #pragma unroll
        for (int rg = 0; rg < 2; ++rg) {
            ap[rg][0] = ldfrag(&lP[(wave * 32 + rg * 16 + l16) * 72 + quad * 8]);
            ap[rg][1] = ldfrag(&lP[(wave * 32 + rg * 16 + l16) * 72 + 32 + quad * 8]);
        }
        bf16x8 vf[4][2];
        #pragma unroll
        for (int ni = 0; ni < 4; ++ni) {
            vf[ni][0] = ldfrag(&lV[(ni * 16 + l16) * 72 + quad * 8]);
            vf[ni][1] = ldfrag(&lV[(ni * 16 + l16) * 72 + 32 + quad * 8]);
        }
        #pragma unroll
        for (int rg = 0; rg < 2; ++rg)
            #pragma unroll
            for (int ni = 0; ni < 4; ++ni) {
                o[rg][ni] = mfma16(ap[rg][0], vf[ni][0], o[rg][ni]);
                o[rg][ni] = mfma16(ap[rg][1], vf[ni][1], o[rg][ni]);
            }
    }
    // one denominator reduction across the 16 l16-lanes of each quad group
    #pragma unroll
    for (int off = 1; off < 16; off <<= 1)
        #pragma unroll
        for (int rg = 0; rg < 2; ++rg)
            #pragma unroll
            for (int r = 0; r < 4; ++r)
                ps_acc[rg][r] += __shfl_xor(ps_acc[rg][r], off);
    float rl[2][4];
    #pragma unroll
    for (int rg = 0; rg < 2; ++rg)
        #pragma unroll
        for (int r = 0; r < 4; ++r) rl[rg][r] = 1.f / ps_acc[rg][r];
    #pragma unroll
    for (int rg = 0; rg < 2; ++rg)
        #pragma unroll
        for (int ni = 0; ni < 4; ++ni)
            #pragma unroll
            for (int r = 0; r < 4; ++r) {
                const int row = q0 + wave * 32 + rg * 16 + quad * 4 + r;
                attb[(size_t)(bb * 1024 + row) * 1024 + h * 64 + ni * 16 + l16] =
                    f2bf_hw(o[rg][ni][r] * rl[rg][r]);
            }
}

// ---------- residual + split-K combine + LayerNorm ----------
__global__ __launch_bounds__(256) void ln_res(const float* __restrict__ y,
                                              const u16* __restrict__ xp0,
                                              const u16* __restrict__ xp1,
                                              const float* __restrict__ a2,
                                              const float* __restrict__ b2,
                                              float* __restrict__ out) {
    const int row = blockIdx.x, tid = threadIdx.x;
    const size_t base = (size_t)row * 1024;
    const int j = tid * 4;
    const float4 yv = *(const float4*)&y[base + j];
    const u16x4 x0 = *(const u16x4*)&xp0[base + j];
    const u16x4 x1 = *(const u16x4*)&xp1[base + j];
    float x[4] = {yv.x + bf2f(x0.x) + bf2f(x1.x),
                  yv.y + bf2f(x0.y) + bf2f(x1.y),
                  yv.z + bf2f(x0.z) + bf2f(x1.z),
                  yv.w + bf2f(x0.w) + bf2f(x1.w)};
    float s = 0.f, ss = 0.f;
    #pragma unroll
    for (int i = 0; i < 4; ++i) { s += x[i]; ss += x[i] * x[i]; }
    #pragma unroll
    for (int off = 1; off < 64; off <<= 1) {
        s += __shfl_xor(s, off);
        ss += __shfl_xor(ss, off);
    }
    __shared__ float rs[4], rss[4];
    const int wave = tid >> 6, lane = tid & 63;
    if (lane == 0) { rs[wave] = s; rss[wave] = ss; }
    __syncthreads();
    s = rs[0] + rs[1] + rs[2] + rs[3];
    ss = rss[0] + rss[1] + rss[2] + rss[3];
    const float mean = s * (1.f / 1024.f);
    float var = (ss - s * mean) * (1.f / 1023.f);
    var = fmaxf(var, 0.f);
    const float inv = 1.f / (sqrtf(var) + 1e-6f);
    const float4 av = *(const float4*)&a2[j];
    const float4 bv = *(const float4*)&b2[j];
    float4 ov;
    ov.x = av.x * (x[0] - mean) * inv + bv.x;
    ov.y = av.y * (x[1] - mean) * inv + bv.y;
    ov.z = av.z * (x[2] - mean) * inv + bv.z;
    ov.w = av.w * (x[3] - mean) * inv + bv.w;
    *(float4*)&out[base + j] = ov;
}

extern "C" void kernel_launch(void* const* d_in, const int* in_sizes, int n_in,
                              void* d_out, int out_size, void* d_ws, size_t ws_size,
                              hipStream_t stream) {
    (void)in_sizes; (void)n_in; (void)out_size;
    const float* y   = (const float*)d_in[0];
    const int*   msk = (const int*)d_in[1];
    const float* Wq  = (const float*)d_in[2];
    const float* bq  = (const float*)d_in[3];
    const float* Wk  = (const float*)d_in[4];
    const float* bkb = (const float*)d_in[5];
    const float* Wv  = (const float*)d_in[6];
    const float* bv  = (const float*)d_in[7];
    const float* Wm  = (const float*)d_in[8];
    const float* bm  = (const float*)d_in[9];
    const float* a2  = (const float*)d_in[10];
    const float* b2  = (const float*)d_in[11];
    float* out = (float*)d_out;

    char* ws = (char*)d_ws;
    const size_t MB = 1u << 20;
    if (ws_size < 72 * MB) return;  // need 72 MB of scratch
    u16* yb  = (u16*)(ws);             // 16 MB (reused as attb after QKV GEMM)
    u16* wqb = (u16*)(ws + 16 * MB);   // wq/wk/wv/wm contiguous (8 MB)
    u16* wmb = (u16*)(ws + 22 * MB);
    u16* qb  = (u16*)(ws + 24 * MB);   // 16 MB (reused as xp0 after attn)
    u16* kb  = (u16*)(ws + 40 * MB);   // 16 MB (reused as xp1 after attn)
    u16* vb  = (u16*)(ws + 56 * MB);   // 16 MB (attn reads it live)
    u16* attb = yb;   // yb dead after QKV GEMM
    u16* xp0  = qb;   // qb dead after attn
    u16* xp1  = kb;   // kb dead after attn

    // idx/cnt scratch lives in d_out (32 MB, dead until ln_res writes it)
    int* idxb = (int*)d_out;           // 8 x 1024 ints
    int* cntb = idxb + 8192;           // 8 ints

    conv_all<<<12289, 256, 0, stream>>>(y, Wq, Wk, Wv, Wm, yb, wqb,
                                        msk, idxb, cntb);

    // fused QKV: Bt = [Wq;Wk;Wv], N=3072, n fast in grid (L2-friendly ordering)
    gemm_bt<<<dim3(24, 64), 256, 0, stream>>>(
        yb, wqb, bq, bkb, bv, qb, kb, vb, 1024);

    attn<<<dim3(1024), 256, 0, stream>>>(qb, kb, vb, idxb, cntb, attb);

    // M-proj split-K: 1024 blocks = 4/CU, halves -> xp0 (with bias) / xp1
    gemm_sk<<<dim3(16, 64), 256, 0, stream>>>(attb, wmb, bm, xp0, xp1);

    ln_res<<<8192, 256, 0, stream>>>(y, xp0, xp1, a2, b2, out);
}

// Round 11
// 276.245 us; speedup vs baseline: 1.0548x; 1.0548x over previous
//
#include <hip/hip_runtime.h>

#define DEVFN __device__ __forceinline__

typedef unsigned short u16;
typedef __attribute__((ext_vector_type(8))) unsigned short u16x8;
typedef __attribute__((ext_vector_type(4))) unsigned short u16x4;
typedef __attribute__((ext_vector_type(8))) __bf16 bf16x8;
typedef __attribute__((ext_vector_type(4))) float f32x4;

// ---------- helpers ----------
DEVFN u16 f2bf_hw(float f) {  // hardware RNE convert (single v_cvt)
    return __builtin_bit_cast(u16, (__bf16)f);
}

DEVFN float bf2f(u16 h) {
    unsigned u = (unsigned)h << 16;
    return __builtin_bit_cast(float, u);
}

DEVFN bf16x8 ldfrag(const u16* p) {
    return __builtin_bit_cast(bf16x8, *(const u16x8*)p);
}

DEVFN f32x4 mfma16(bf16x8 a, bf16x8 b, f32x4 c) {
    return __builtin_amdgcn_mfma_f32_16x16x32_bf16(a, b, c, 0, 0, 0);
}

// async global->LDS, 16B per lane; l must be the wave-uniform base
DEVFN void async16(const u16* g, u16* l) {
    __builtin_amdgcn_global_load_lds(
        (const __attribute__((address_space(1))) void*)g,
        (__attribute__((address_space(3))) void*)l, 16, 0, 0);
}

// ---------- fp32->bf16 converts + mask compaction, ONE dispatch ----------
// blocks 0..8191: y. 8192..12287: weights. block 12288: mask compaction.
__global__ __launch_bounds__(256) void conv_all(const float* __restrict__ y,
                                                const float* __restrict__ w0,
                                                const float* __restrict__ w1,
                                                const float* __restrict__ w2,
                                                const float* __restrict__ w3,
                                                u16* __restrict__ yb,
                                                u16* __restrict__ wb,
                                                const int* __restrict__ mask,
                                                int* __restrict__ idx,
                                                int* __restrict__ cnt) {
    const int b = blockIdx.x;
    if (b >= 12288) {
        const int wave = threadIdx.x >> 6, lane = threadIdx.x & 63;
        for (int bb = wave; bb < 8; bb += 4) {
            const int* m = mask + bb * 1024;
            int* ib = idx + bb * 1024;
            int base = 0;
            for (int t = 0; t < 16; ++t) {
                const int pos = t * 64 + lane;
                const int valid = (m[pos] == 0) ? 1 : 0;
                const unsigned long long bal = __ballot(valid);
                const int pre = __popcll(bal & ((1ull << lane) - 1ull));
                if (valid) ib[base + pre] = pos;
                base += (int)__popcll(bal);
            }
            if (lane == 0) cnt[bb] = base;
            for (int i = base + lane; i < 1024; i += 64) ib[i] = 0;  // safe pad
        }
        return;
    }
    const float* src;
    u16* dst;
    int i;
    if (b < 8192) {
        src = y; dst = yb;
        i = b * 1024 + threadIdx.x * 4;
    } else {
        const int g = (b - 8192) >> 10;
        src = g == 0 ? w0 : (g == 1 ? w1 : (g == 2 ? w2 : w3));
        dst = wb + (size_t)g * 1024 * 1024;
        i = ((b - 8192) & 1023) * 1024 + threadIdx.x * 4;
    }
    const float4 v = *(const float4*)&src[i];
    u16x4 o;
    o.x = f2bf_hw(v.x); o.y = f2bf_hw(v.y);
    o.z = f2bf_hw(v.z); o.w = f2bf_hw(v.w);
    *(u16x4*)&dst[i] = o;
}

// ---------- GEMM: C[M,N] = A[M,K] * Bt[N,K]^T + bias, bf16 out ----------
// EXACT round-7 kernel (73.4 us QKV, MfmaUtil 28.7%). Lessons locked in:
// R4/R10: block-granularity changes (XCD m-streaming, split-K) lose to fixed
// per-block overheads; R5: BK=64 loses to occupancy; R8: genericizing this
// signature degrades the K-loop schedule. Keep untouched.
// BK=32, n-fast 2D grid, launch_bounds(256,4) -> 56 VGPR, ~32% occupancy.
// Output split by col>>10 into up to 3 dense [M,1024] buffers (QKV fusion).
__global__ __launch_bounds__(256, 4) void gemm_bt(const u16* __restrict__ A,
                                                  const u16* __restrict__ Bt,
                                                  const float* __restrict__ b0,
                                                  const float* __restrict__ b1,
                                                  const float* __restrict__ b2,
                                                  u16* __restrict__ C0,
                                                  u16* __restrict__ C1,
                                                  u16* __restrict__ C2,
                                                  int K) {
    __shared__ u16 lA[128 * 32];
    __shared__ u16 lB[128 * 32];
    const int tid = threadIdx.x;
    const int wave = tid >> 6, lane = tid & 63;
    const int quad = lane >> 4, l16 = lane & 15;
    const int n0 = blockIdx.x * 128, m0 = blockIdx.y * 128;
    const int wm = (wave >> 1) * 64, wn = (wave & 1) * 64;
    const int srow = tid >> 2, scol = (tid & 3) * 8;
    const u16* Ag0 = A + (size_t)(m0 + srow) * K + scol;
    const u16* Ag1 = A + (size_t)(m0 + 64 + srow) * K + scol;
    const u16* Bg0 = Bt + (size_t)(n0 + srow) * K + scol;
    const u16* Bg1 = Bt + (size_t)(n0 + 64 + srow) * K + scol;
    u16* lA0 = &lA[wave * 512];
    u16* lA1 = &lA[2048 + wave * 512];
    u16* lB0 = &lB[wave * 512];
    u16* lB1 = &lB[2048 + wave * 512];
    f32x4 acc[4][4] = {};
    for (int k0 = 0; k0 < K; k0 += 32) {
        __syncthreads();
        async16(Ag0 + k0, lA0);
        async16(Ag1 + k0, lA1);
        async16(Bg0 + k0, lB0);
        async16(Bg1 + k0, lB1);
        __syncthreads();
        bf16x8 af[4], bfr[4];
        #pragma unroll
        for (int i = 0; i < 4; ++i)
            af[i] = ldfrag(&lA[(wm + i * 16 + l16) * 32 + quad * 8]);
        #pragma unroll
        for (int i = 0; i < 4; ++i)
            bfr[i] = ldfrag(&lB[(wn + i * 16 + l16) * 32 + quad * 8]);
        #pragma unroll
        for (int mi = 0; mi < 4; ++mi)
            #pragma unroll
            for (int ni = 0; ni < 4; ++ni)
                acc[mi][ni] = mfma16(af[mi], bfr[ni], acc[mi][ni]);
    }
    #pragma unroll
    for (int mi = 0; mi < 4; ++mi) {
        #pragma unroll
        for (int ni = 0; ni < 4; ++ni) {
            const int col = n0 + wn + ni * 16 + l16;
            const int cs = col >> 10;          // uniform per 16-col group
            const int c = col & 1023;
            const float* bp = cs == 0 ? b0 : (cs == 1 ? b1 : b2);
            u16* cp = cs == 0 ? C0 : (cs == 1 ? C1 : C2);
            const float bb = bp[c];
            #pragma unroll
            for (int r = 0; r < 4; ++r) {
                const int row = m0 + wm + mi * 16 + quad * 4 + r;
                cp[(size_t)row * 1024 + c] = f2bf_hw(acc[mi][ni][r] + bb);
            }
        }
    }
}

// ---------- flash attention over COMPACTED K/V, in-kernel V transpose ----------
// Only unmasked K-positions processed (math identical: masked cols had
// exp(-1e9)=0 exactly). 128 q-rows/block, each wave owns 2x16 rows.
__global__ __launch_bounds__(256) void attn(const u16* __restrict__ qb,
                                            const u16* __restrict__ kb,
                                            const u16* __restrict__ vb,
                                            const int* __restrict__ idxb,
                                            const int* __restrict__ cntb,
                                            u16* __restrict__ attb) {
    // XCD swizzle: 8 q-tiles of one (b,h) land on one XCD; 16 heads/XCD
    // keeps that XCD's K+V (4 MB) resident in its L2.
    const int lin = blockIdx.x;
    const int xcd = lin & 7, slot = lin >> 3;          // slot 0..127
    const int bh = xcd * 16 + (slot >> 3);
    const int q0 = (slot & 7) * 128;
    const int bb = bh >> 4, h = bh & 15;
    const int tid = threadIdx.x, wave = tid >> 6, lane = tid & 63;
    const int quad = lane >> 4, l16 = lane & 15;
    __shared__ u16 lK[64 * 72];
    __shared__ u16 lV[64 * 72];
    __shared__ u16 lP[128 * 72];

    const int cn = cntb[bb];
    const int kEnd = (cn + 63) & ~63;
    const int* ib = idxb + bb * 1024;

    // Q fragments: 2 row-groups x 2 k-halves
    bf16x8 aq[2][2];
    #pragma unroll
    for (int rg = 0; rg < 2; ++rg) {
        const int qrow = q0 + wave * 32 + rg * 16 + l16;
        const u16* qp = qb + (size_t)(bb * 1024 + qrow) * 1024 + h * 64 + quad * 8;
        aq[rg][0] = ldfrag(qp);
        aq[rg][1] = ldfrag(qp + 32);
    }

    f32x4 o[2][4] = {};
    float ps_acc[2][4] = {};

    const int srow = tid >> 3, scol = (tid & 7) * 8;
    const u16* kbase = kb + (size_t)(bb * 1024) * 1024 + h * 64 + scol;
    const u16* vbase = vb + (size_t)(bb * 1024) * 1024 + h * 64 + scol;

    // prefetch tile 0: K and V rows gathered via idx (same gi for both)
    int gi0 = ib[srow], gi1 = ib[srow + 32];
    u16x8 nk0 = *(const u16x8*)(kbase + (size_t)gi0 * 1024);
    u16x8 nk1 = *(const u16x8*)(kbase + (size_t)gi1 * 1024);
    u16x8 nv0 = *(const u16x8*)(vbase + (size_t)gi0 * 1024);
    u16x8 nv1 = *(const u16x8*)(vbase + (size_t)gi1 * 1024);

    const float C = 0.18033688011112043f;  // 0.125 * log2(e)

    for (int kt = 0; kt < kEnd; kt += 64) {
        __syncthreads();
        *(u16x8*)&lK[srow * 72 + scol] = nk0;
        *(u16x8*)&lK[(srow + 32) * 72 + scol] = nk1;
        // V written transposed: lV[d][slot]; ~2-way bank aliasing (free).
        #pragma unroll
        for (int j = 0; j < 8; ++j) {
            lV[(scol + j) * 72 + srow] = nv0[j];
            lV[(scol + j) * 72 + srow + 32] = nv1[j];
        }
        __syncthreads();
        const int ktn = kt + 64;
        if (ktn < kEnd) {  // prefetch next tile; vmcnt hidden behind compute
            gi0 = ib[ktn + srow]; gi1 = ib[ktn + srow + 32];
            nk0 = *(const u16x8*)(kbase + (size_t)gi0 * 1024);
            nk1 = *(const u16x8*)(kbase + (size_t)gi1 * 1024);
            nv0 = *(const u16x8*)(vbase + (size_t)gi0 * 1024);
            nv1 = *(const u16x8*)(vbase + (size_t)gi1 * 1024);
        }

        // K fragments loaded once, reused by both row-groups
        bf16x8 kf[4][2];
        #pragma unroll
        for (int n = 0; n < 4; ++n) {
            kf[n][0] = ldfrag(&lK[(n * 16 + l16) * 72 + quad * 8]);
            kf[n][1] = ldfrag(&lK[(n * 16 + l16) * 72 + 32 + quad * 8]);
        }
        f32x4 s[2][4];
        #pragma unroll
        for (int rg = 0; rg < 2; ++rg)
            #pragma unroll
            for (int n = 0; n < 4; ++n) {
                f32x4 t = {};
                t = mfma16(aq[rg][0], kf[n][0], t);
                t = mfma16(aq[rg][1], kf[n][1], t);
                s[rg][n] = t;
            }
        float bias[4];
        #pragma unroll
        for (int n = 0; n < 4; ++n)
            bias[n] = (kt + n * 16 + l16 < cn) ? 0.0f : -1e9f;
        #pragma unroll
        for (int rg = 0; rg < 2; ++rg)
            #pragma unroll
            for (int n = 0; n < 4; ++n)
                #pragma unroll
                for (int r = 0; r < 4; ++r) {
                    const float p =
                        __builtin_amdgcn_exp2f(__builtin_fmaf(s[rg][n][r], C, bias[n]));
                    ps_acc[rg][r] += p;
                    lP[(wave * 32 + rg * 16 + quad * 4 + r) * 72 + n * 16 + l16] =
                        f2bf_hw(p);
                }
        // lP rows are wave-private: drain this wave's LDS ops, no barrier
        __asm__ __volatile__("s_waitcnt lgkmcnt(0)" ::: "memory");
        bf16x8 ap[2][2];
        #pragma unroll
        for (int rg = 0; rg < 2; ++rg) {
            ap[rg][0] = ldfrag(&lP[(wave * 32 + rg * 16 + l16) * 72 + quad * 8]);
            ap[rg][1] = ldfrag(&lP[(wave * 32 + rg * 16 + l16) * 72 + 32 + quad * 8]);
        }
        bf16x8 vf[4][2];
        #pragma unroll
        for (int ni = 0; ni < 4; ++ni) {
            vf[ni][0] = ldfrag(&lV[(ni * 16 + l16) * 72 + quad * 8]);
            vf[ni][1] = ldfrag(&lV[(ni * 16 + l16) * 72 + 32 + quad * 8]);
        }
        #pragma unroll
        for (int rg = 0; rg < 2; ++rg)
            #pragma unroll
            for (int ni = 0; ni < 4; ++ni) {
                o[rg][ni] = mfma16(ap[rg][0], vf[ni][0], o[rg][ni]);
                o[rg][ni] = mfma16(ap[rg][1], vf[ni][1], o[rg][ni]);
            }
    }
    // one denominator reduction across the 16 l16-lanes of each quad group
    #pragma unroll
    for (int off = 1; off < 16; off <<= 1)
        #pragma unroll
        for (int rg = 0; rg < 2; ++rg)
            #pragma unroll
            for (int r = 0; r < 4; ++r)
                ps_acc[rg][r] += __shfl_xor(ps_acc[rg][r], off);
    float rl[2][4];
    #pragma unroll
    for (int rg = 0; rg < 2; ++rg)
        #pragma unroll
        for (int r = 0; r < 4; ++r) rl[rg][r] = 1.f / ps_acc[rg][r];
    #pragma unroll
    for (int rg = 0; rg < 2; ++rg)
        #pragma unroll
        for (int ni = 0; ni < 4; ++ni)
            #pragma unroll
            for (int r = 0; r < 4; ++r) {
                const int row = q0 + wave * 32 + rg * 16 + quad * 4 + r;
                attb[(size_t)(bb * 1024 + row) * 1024 + h * 64 + ni * 16 + l16] =
                    f2bf_hw(o[rg][ni][r] * rl[rg][r]);
            }
}

// ---------- residual (bf16 y) + LayerNorm (torch: unbiased std, eps on std) ----------
__global__ __launch_bounds__(256) void ln_res(const u16* __restrict__ ybf,
                                              const u16* __restrict__ xpb,
                                              const float* __restrict__ a2,
                                              const float* __restrict__ b2,
                                              float* __restrict__ out) {
    const int row = blockIdx.x, tid = threadIdx.x;
    const size_t base = (size_t)row * 1024;
    const int j = tid * 4;
    const u16x4 yv = *(const u16x4*)&ybf[base + j];
    const u16x4 xv = *(const u16x4*)&xpb[base + j];
    float x[4] = {bf2f(yv.x) + bf2f(xv.x), bf2f(yv.y) + bf2f(xv.y),
                  bf2f(yv.z) + bf2f(xv.z), bf2f(yv.w) + bf2f(xv.w)};
    float s = 0.f, ss = 0.f;
    #pragma unroll
    for (int i = 0; i < 4; ++i) { s += x[i]; ss += x[i] * x[i]; }
    #pragma unroll
    for (int off = 1; off < 64; off <<= 1) {
        s += __shfl_xor(s, off);
        ss += __shfl_xor(ss, off);
    }
    __shared__ float rs[4], rss[4];
    const int wave = tid >> 6, lane = tid & 63;
    if (lane == 0) { rs[wave] = s; rss[wave] = ss; }
    __syncthreads();
    s = rs[0] + rs[1] + rs[2] + rs[3];
    ss = rss[0] + rss[1] + rss[2] + rss[3];
    const float mean = s * (1.f / 1024.f);
    float var = (ss - s * mean) * (1.f / 1023.f);
    var = fmaxf(var, 0.f);
    const float inv = 1.f / (sqrtf(var) + 1e-6f);
    const float4 av = *(const float4*)&a2[j];
    const float4 bv = *(const float4*)&b2[j];
    float4 ov;
    ov.x = av.x * (x[0] - mean) * inv + bv.x;
    ov.y = av.y * (x[1] - mean) * inv + bv.y;
    ov.z = av.z * (x[2] - mean) * inv + bv.z;
    ov.w = av.w * (x[3] - mean) * inv + bv.w;
    *(float4*)&out[base + j] = ov;
}

extern "C" void kernel_launch(void* const* d_in, const int* in_sizes, int n_in,
                              void* d_out, int out_size, void* d_ws, size_t ws_size,
                              hipStream_t stream) {
    (void)in_sizes; (void)n_in; (void)out_size;
    const float* y   = (const float*)d_in[0];
    const int*   msk = (const int*)d_in[1];
    const float* Wq  = (const float*)d_in[2];
    const float* bq  = (const float*)d_in[3];
    const float* Wk  = (const float*)d_in[4];
    const float* bkb = (const float*)d_in[5];
    const float* Wv  = (const float*)d_in[6];
    const float* bv  = (const float*)d_in[7];
    const float* Wm  = (const float*)d_in[8];
    const float* bm  = (const float*)d_in[9];
    const float* a2  = (const float*)d_in[10];
    const float* b2  = (const float*)d_in[11];
    float* out = (float*)d_out;

    char* ws = (char*)d_ws;
    const size_t MB = 1u << 20;
    if (ws_size < 72 * MB) return;  // need 72 MB of scratch
    u16* yb  = (u16*)(ws);             // 16 MB, stays LIVE (ln_res reads it)
    u16* wqb = (u16*)(ws + 16 * MB);   // wq/wk/wv/wm contiguous (8 MB)
    u16* wmb = (u16*)(ws + 22 * MB);
    u16* qb  = (u16*)(ws + 24 * MB);   // 16 MB (reused as bf16 xp after attn)
    u16* kb  = (u16*)(ws + 40 * MB);   // 16 MB
    u16* vb  = (u16*)(ws + 56 * MB);   // 16 MB (attn reads it live)
    u16* xpb  = qb;   // qb dead after attn

    // d_out (32 MB) is dead until ln_res: idx/cnt in first 33 KB (read by
    // attn), attb in the second 16 MB (written by attn, read by mproj which
    // completes before ln_res overwrites everything, stream-ordered).
    int* idxb = (int*)d_out;                       // 8 x 1024 ints
    int* cntb = idxb + 8192;                       // 8 ints
    u16* attb = (u16*)((char*)d_out + 16 * MB);    // 16 MB

    conv_all<<<12289, 256, 0, stream>>>(y, Wq, Wk, Wv, Wm, yb, wqb,
                                        msk, idxb, cntb);

    // fused QKV: Bt = [Wq;Wk;Wv], N=3072, n fast in grid (L2-friendly ordering)
    gemm_bt<<<dim3(24, 64), 256, 0, stream>>>(
        yb, wqb, bq, bkb, bv, qb, kb, vb, 1024);

    attn<<<dim3(1024), 256, 0, stream>>>(qb, kb, vb, idxb, cntb, attb);

    // M-proj: N=1024, bf16 out (round-9 proven config, unsplit)
    gemm_bt<<<dim3(8, 64), 256, 0, stream>>>(
        attb, wmb, bm, bm, bm, xpb, xpb, xpb, 1024);

    ln_res<<<8192, 256, 0, stream>>>(yb, xpb, a2, b2, out);
}